// Round 3
// baseline (1790.441 us; speedup 1.0000x reference)
//
#include <hip/hip_runtime.h>
#include <hip/hip_bf16.h>

// RGCN layer: out = x@W_self + b_self + sum_t [ mean_t(x[src]) @ W[t] + (deg_t>0)*b[t] ]
// v4 (2nd resubmit; rounds 1-2 hit GPUAcquisitionTimeout, never measured):
//     k_fused rebuilt around edge-parallel aggregation (the gather was latency-bound
//     at 29% occupancy with a serial per-node degree loop):
//     - eid now packs (src<<6)|dst_local; each block consumes its tile's contiguous
//       per-etype edge range 128 edges/iteration -> all gather loads independent.
//     - segment-sum via LDS f32 atomicAdd into a 32KB accumulator, XOR-swizzled by
//       dst_local (5-bit key) so random rows spread across all 32 banks.
//     - w_s dropped from LDS (B-frags from global wt, L1/L2-resident); bf16 a_s
//       aliases the f32 accumulator -> LDS 52KB -> 32KB -> 4 blocks/CU.
//     - mean divide fused into the f32->bf16 convert phase (scale rows by 1/deg).

namespace {

constexpr int N  = 200000;  // nodes
constexpr int T  = 4;       // etypes
constexpr int E  = 500000;  // edges per etype
constexpr int D  = 128;     // d_in == d_out
constexpr int NT = 64;      // nodes per block tile

constexpr int CNT_B = (T * E + 255) / 256;      // 7813
constexpr int PX_B  = (N * D / 8) / 256;        // 12500 (exact)
constexpr int PW_B  = (5 * D * D / 8 + 255) / 256;  // 40

typedef __bf16 bf16x8 __attribute__((ext_vector_type(8)));
typedef float  f32x4  __attribute__((ext_vector_type(4)));

__global__ void k_zero(int* __restrict__ p, int n) {
  int i = blockIdx.x * 256 + threadIdx.x;
  if (i < n) p[i] = 0;
}

// Fused: edge count (+rank) | x fp32->bf16 | W^T pack to bf16.
template <bool XB>
__global__ void k_prep(const int* __restrict__ dst, int* __restrict__ cnt,
                       int* __restrict__ rank, const float* __restrict__ x,
                       __bf16* __restrict__ xb, const float* __restrict__ W,
                       const float* __restrict__ Wself, __bf16* __restrict__ wt) {
  const int bid = blockIdx.x;
  const int tid = threadIdx.x;
  if (bid < CNT_B) {
    int i = bid * 256 + tid;
    if (i < T * E) {
      int t = i / E;
      rank[i] = atomicAdd(&cnt[t * N + dst[i]], 1);
    }
  } else if (XB && bid < CNT_B + PX_B) {
    int i = (bid - CNT_B) * 256 + tid;  // one per 8 floats
    if (i < N * D / 8) {
      const float4* xs = (const float4*)(x + i * 8);
      float4 a = xs[0], c = xs[1];
      bf16x8 v;
      v[0] = (__bf16)a.x; v[1] = (__bf16)a.y; v[2] = (__bf16)a.z; v[3] = (__bf16)a.w;
      v[4] = (__bf16)c.x; v[5] = (__bf16)c.y; v[6] = (__bf16)c.z; v[7] = (__bf16)c.w;
      *(bf16x8*)(xb + i * 8) = v;
    }
  } else {
    int i = (bid - CNT_B - (XB ? PX_B : 0)) * 256 + tid;  // one per 8 wt elems
    if (i < 5 * D * D / 8) {
      int base = i * 8;
      int p = base >> 14, rem = base & 16383;
      int n = rem >> 7, k0 = rem & 127;
      const float* Wsrc = (p < 4) ? (W + (size_t)p * D * D) : Wself;  // [k][n]
      bf16x8 v;
#pragma unroll
      for (int j = 0; j < 8; ++j) v[j] = (__bf16)Wsrc[(k0 + j) * D + n];
      *(bf16x8*)(wt + base) = v;
    }
  }
}

// Exclusive offsets via block scan + one global-cursor atomic per block.
// NOTE: offsets are monotone/contiguous only WITHIN a 256-bucket scan block;
// a 64-node tile (64-aligned, N%64==0) never straddles one, which k_fused
// relies on for its contiguous per-tile edge range.
__global__ void k_offsets(const int* __restrict__ cnt, int* __restrict__ offs,
                          int* __restrict__ cursor) {
  __shared__ int s[256];
  __shared__ int base;
  int tid = threadIdx.x;
  int i = blockIdx.x * 256 + tid;
  int c = (i < T * N) ? cnt[i] : 0;
  s[tid] = c;
  __syncthreads();
  for (int d = 1; d < 256; d <<= 1) {
    int v = (tid >= d) ? s[tid - d] : 0;
    __syncthreads();
    s[tid] += v;
    __syncthreads();
  }
  if (tid == 255) base = atomicAdd(cursor, s[255]);
  __syncthreads();
  if (i < T * N) offs[i] = base + s[tid] - c;  // exclusive
}

// No atomics: pos = offs[bucket] + rank. Value packs (src, dst_local).
__global__ void k_scatter(const int* __restrict__ src, const int* __restrict__ dst,
                          const int* __restrict__ offs, const int* __restrict__ rank,
                          int* __restrict__ eid) {
  int i = blockIdx.x * 256 + threadIdx.x;
  if (i >= T * E) return;
  int t = i / E;
  int d = dst[i];
  int pos = offs[t * N + d] + rank[i];
  eid[pos] = (src[i] << 6) | (d & 63);  // src < 2^18, dst_local 6 bits
}

// Fused aggregate + bf16 MFMA GEMM. 256 threads (4 waves), 64-node tile.
// LDS: 32 KiB f32 accumulator (bf16 a_s aliased in) -> 4 blocks/CU.
template <bool XB>
__global__ __launch_bounds__(256, 4) void k_fused(
    const float* __restrict__ x, const __bf16* __restrict__ xb,
    const __bf16* __restrict__ wt, const float* __restrict__ b,
    const float* __restrict__ bself, const int* __restrict__ cnt,
    const int* __restrict__ offs, const int* __restrict__ eid,
    float* __restrict__ out) {
  __shared__ __align__(16) float accf[NT * D];  // 32 KiB

  const int tid  = threadIdx.x;
  const int nb   = blockIdx.x * NT;
  const int wv   = tid >> 6;
  const int lane = tid & 63;
  const int quad = lane >> 4;
  const int l16  = lane & 15;
  const int grp  = tid >> 2;   // edge-group / row 0..63
  const int q    = tid & 3;    // 32-col quarter

  f32x4 acc[8];
#pragma unroll
  for (int ct = 0; ct < 8; ++ct) acc[ct] = (f32x4){0.f, 0.f, 0.f, 0.f};

  for (int pass = 0; pass < 5; ++pass) {
    const bool self = (pass == 4);

    if (!self) {
      if (pass) __syncthreads();  // prev MFMA finished reading aliased a_s
      {                           // zero f32 accumulator
        f32x4* z4 = (f32x4*)accf;
        const f32x4 z = {0.f, 0.f, 0.f, 0.f};
#pragma unroll
        for (int k2 = 0; k2 < 8; ++k2) z4[k2 * 256 + tid] = z;
      }
      __syncthreads();

      const int b0    = pass * N + nb;
      const int base  = offs[b0];
      const int nedge = offs[b0 + NT - 1] + cnt[b0 + NT - 1] - base;

      // ---- edge-parallel gather + LDS atomic segment-sum.
      // Storage swizzle: logical col c of row r lives at c ^ (r & 31)
      // (bits 0-4 XOR -> random rows spread atomics over all 32 banks).
      for (int it = 0; it < nedge; it += 128) {
        const int i0 = it + grp;
        const int i1 = i0 + 64;
        const int u0 = (i0 < nedge) ? eid[base + i0] : 0;
        const int u1 = (i1 < nedge) ? eid[base + i1] : 0;
        if (XB) {
          const char* p0 = (const char*)(xb + (size_t)(u0 >> 6) * D + q * 8);
          const char* p1 = (const char*)(xb + (size_t)(u1 >> 6) * D + q * 8);
          int4 m0[4], m1[4];
#pragma unroll
          for (int l = 0; l < 4; ++l) m0[l] = *(const int4*)(p0 + l * 64);
#pragma unroll
          for (int l = 0; l < 4; ++l) m1[l] = *(const int4*)(p1 + l * 64);
          if (i0 < nedge) {
            const int dl  = u0 & 63;
            const int key = dl & 31;
            float* rowp = accf + dl * 128;
#pragma unroll
            for (int l = 0; l < 4; ++l) {
              const unsigned uu[4] = {(unsigned)m0[l].x, (unsigned)m0[l].y,
                                      (unsigned)m0[l].z, (unsigned)m0[l].w};
#pragma unroll
              for (int p2 = 0; p2 < 4; ++p2) {
                const int c0 = l * 32 + q * 8 + 2 * p2;
                atomicAdd(rowp + (c0 ^ key), __uint_as_float(uu[p2] << 16));
                atomicAdd(rowp + ((c0 + 1) ^ key),
                          __uint_as_float(uu[p2] & 0xffff0000u));
              }
            }
          }
          if (i1 < nedge) {
            const int dl  = u1 & 63;
            const int key = dl & 31;
            float* rowp = accf + dl * 128;
#pragma unroll
            for (int l = 0; l < 4; ++l) {
              const unsigned uu[4] = {(unsigned)m1[l].x, (unsigned)m1[l].y,
                                      (unsigned)m1[l].z, (unsigned)m1[l].w};
#pragma unroll
              for (int p2 = 0; p2 < 4; ++p2) {
                const int c0 = l * 32 + q * 8 + 2 * p2;
                atomicAdd(rowp + (c0 ^ key), __uint_as_float(uu[p2] << 16));
                atomicAdd(rowp + ((c0 + 1) ^ key),
                          __uint_as_float(uu[p2] & 0xffff0000u));
              }
            }
          }
        } else {
          const float* p0 = x + (size_t)(u0 >> 6) * D + q * 8;
          const float* p1 = x + (size_t)(u1 >> 6) * D + q * 8;
          f32x4 a0[8], a1[8];
#pragma unroll
          for (int l = 0; l < 4; ++l) {
            a0[2 * l]     = *(const f32x4*)(p0 + l * 32);
            a0[2 * l + 1] = *(const f32x4*)(p0 + l * 32 + 4);
          }
#pragma unroll
          for (int l = 0; l < 4; ++l) {
            a1[2 * l]     = *(const f32x4*)(p1 + l * 32);
            a1[2 * l + 1] = *(const f32x4*)(p1 + l * 32 + 4);
          }
          if (i0 < nedge) {
            const int dl  = u0 & 63;
            const int key = dl & 31;
            float* rowp = accf + dl * 128;
#pragma unroll
            for (int l = 0; l < 4; ++l)
#pragma unroll
              for (int w = 0; w < 4; ++w) {
                const int c0 = l * 32 + q * 8 + w;
                atomicAdd(rowp + (c0 ^ key), a0[2 * l][w]);
                atomicAdd(rowp + ((c0 + 4) ^ key), a0[2 * l + 1][w]);
              }
          }
          if (i1 < nedge) {
            const int dl  = u1 & 63;
            const int key = dl & 31;
            float* rowp = accf + dl * 128;
#pragma unroll
            for (int l = 0; l < 4; ++l)
#pragma unroll
              for (int w = 0; w < 4; ++w) {
                const int c0 = l * 32 + q * 8 + w;
                atomicAdd(rowp + (c0 ^ key), a1[2 * l][w]);
                atomicAdd(rowp + ((c0 + 4) ^ key), a1[2 * l + 1][w]);
              }
          }
        }
      }
      __syncthreads();

      // ---- mean (x 1/deg) + f32->bf16, into aliased a_s.
      // a_s transform: elem group (c>>3) ^ (row&7), conflict-free MFMA A reads.
      {
        const int ln   = grp;
        const int keyr = ln & 31;
        const int deg  = cnt[b0 + ln];
        const float inv = (deg > 0) ? (1.0f / (float)deg) : 0.f;
        const float* rp = accf + ln * 128;
        float rv[32];
#pragma unroll
        for (int idx = 0; idx < 32; ++idx) rv[idx] = rp[(q * 32 + idx) ^ keyr];
        __syncthreads();
        __bf16* ab = (__bf16*)accf;
#pragma unroll
        for (int g = 0; g < 4; ++g) {
          bf16x8 vv;
#pragma unroll
          for (int j2 = 0; j2 < 8; ++j2) vv[j2] = (__bf16)(rv[g * 8 + j2] * inv);
          *(bf16x8*)(ab + ln * 128 + ((q * 32 + g * 8) ^ ((ln & 7) << 3))) = vv;
        }
      }
      __syncthreads();
    }

    // ---- MFMA: B-frags straight from global wt (L1/L2-resident, 32KB/pass)
#pragma unroll
    for (int ks = 0; ks < 4; ++ks) {
      bf16x8 af;
      if (self) {
        if (XB) {
          af = *(const bf16x8*)(xb + (size_t)(nb + 16 * wv + l16) * D + ks * 32 +
                                quad * 8);
        } else {
          const float* xr =
              x + (size_t)(nb + 16 * wv + l16) * D + ks * 32 + quad * 8;
          f32x4 v0 = *(const f32x4*)xr, v1 = *(const f32x4*)(xr + 4);
#pragma unroll
          for (int j2 = 0; j2 < 4; ++j2) {
            af[j2] = (__bf16)v0[j2];
            af[4 + j2] = (__bf16)v1[j2];
          }
        }
      } else {
        const __bf16* ab = (const __bf16*)accf;
        const int row = 16 * wv + l16;
        af = *(const bf16x8*)(ab + row * 128 +
                              ((ks * 32 + quad * 8) ^ ((row & 7) << 3)));
      }
      const __bf16* wp = wt + pass * D * D + ks * 32 + quad * 8;
#pragma unroll
      for (int ct = 0; ct < 8; ++ct) {
        bf16x8 bfr = *(const bf16x8*)(wp + (16 * ct + l16) * D);
        acc[ct] = __builtin_amdgcn_mfma_f32_16x16x32_bf16(af, bfr, acc[ct], 0, 0, 0);
      }
    }

    // ---- bias: b[t] gated on deg>0 per output row; b_self unconditional.
    // C/D layout: col = 16*ct + l16, row = 16*wv + quad*4 + reg.
    {
      const float* bt = self ? bself : (b + pass * D);
      bool rowon[4];
#pragma unroll
      for (int r = 0; r < 4; ++r) {
        rowon[r] = self ? true : (cnt[pass * N + nb + 16 * wv + quad * 4 + r] > 0);
      }
#pragma unroll
      for (int ct = 0; ct < 8; ++ct) {
        const float bv = bt[16 * ct + l16];
#pragma unroll
        for (int r = 0; r < 4; ++r)
          if (rowon[r]) acc[ct][r] += bv;
      }
    }
  }

  // ---- epilogue: each store covers 64B lines (16 lanes x 4B contiguous)
#pragma unroll
  for (int ct = 0; ct < 8; ++ct) {
#pragma unroll
    for (int r = 0; r < 4; ++r) {
      out[(size_t)(nb + 16 * wv + quad * 4 + r) * D + 16 * ct + l16] = acc[ct][r];
    }
  }
}

}  // namespace

extern "C" void kernel_launch(void* const* d_in, const int* in_sizes, int n_in,
                              void* d_out, int out_size, void* d_ws, size_t ws_size,
                              hipStream_t stream) {
  const float* x     = (const float*)d_in[0];
  const float* W     = (const float*)d_in[1];
  const float* b     = (const float*)d_in[2];
  const float* Wself = (const float*)d_in[3];
  const float* bself = (const float*)d_in[4];
  const int*   src   = (const int*)d_in[5];
  const int*   dst   = (const int*)d_in[6];
  float* out = (float*)d_out;

  // ws (ints): cnt[T*N] | cursor(+pad)[4] | offs[T*N] | eid[T*E] | rank[T*E]
  //            then bf16: wt[5*D*D] | xb[N*D]
  int* cnt    = (int*)d_ws;
  int* cursor = cnt + T * N;
  int* offs   = cursor + 4;
  int* eid    = offs + T * N;
  int* rank   = eid + T * E;
  __bf16* wt  = (__bf16*)(rank + T * E);
  __bf16* xb  = wt + 5 * D * D;

  const size_t need_xb =
      (size_t)(T * N + 4 + T * N + T * E + T * E) * 4 + (size_t)5 * D * D * 2 +
      (size_t)N * D * 2;
  const bool use_xb = ws_size >= need_xb;

  k_zero<<<(T * N + 4 + 255) / 256, 256, 0, stream>>>(cnt, T * N + 4);
  if (use_xb) {
    k_prep<true><<<CNT_B + PX_B + PW_B, 256, 0, stream>>>(dst, cnt, rank, x, xb,
                                                          W, Wself, wt);
  } else {
    k_prep<false><<<CNT_B + PW_B, 256, 0, stream>>>(dst, cnt, rank, x, xb, W,
                                                    Wself, wt);
  }
  k_offsets<<<(T * N + 255) / 256, 256, 0, stream>>>(cnt, offs, cursor);
  k_scatter<<<(T * E + 255) / 256, 256, 0, stream>>>(src, dst, offs, rank, eid);
  if (use_xb) {
    k_fused<true><<<N / NT, 256, 0, stream>>>(x, xb, wt, b, bself, cnt, offs,
                                              eid, out);
  } else {
    k_fused<false><<<N / NT, 256, 0, stream>>>(x, xb, wt, b, bself, cnt, offs,
                                               eid, out);
  }
}

// Round 5
// 783.923 us; speedup vs baseline: 2.2839x; 2.2839x over previous
//
#include <hip/hip_runtime.h>
#include <hip/hip_bf16.h>

// RGCN layer: out = x@W_self + b_self + sum_t [ mean_t(x[src]) @ W[t] + (deg_t>0)*b[t] ]
// v5 (resubmit; prior round hit GPUAcquisitionTimeout, never measured):
//     revert v4's LDS-atomic edge-parallel aggregation (measured 7.2x REGRESSION:
//     256M ds-atomics serialized, VALUBusy 3%). Back to v3's register-accumulating
//     per-node gather, keeping only v4's footprint win:
//     - w_s dropped from LDS; MFMA B-frags read from global wt (L1/L2-resident slab).
//     - LDS 52KB -> 17.4KB (a_s only) => 6 blocks/CU (24 waves) vs v3's 3 blocks.
//       v3's gather was latency-bound (VALU 26%, occ 29%) -> 2x waves to hide it.
//     - launch_bounds(256,6): cap VGPR at ~85 (v3 used 76).

namespace {

constexpr int N  = 200000;  // nodes
constexpr int T  = 4;       // etypes
constexpr int E  = 500000;  // edges per etype
constexpr int D  = 128;     // d_in == d_out
constexpr int NT = 64;      // nodes per block tile
constexpr int AS = 136;     // padded LDS row stride (bf16): 2-way bank alias only (free)

constexpr int CNT_B = (T * E + 255) / 256;      // 7813
constexpr int PX_B  = (N * D / 8) / 256;        // 12500 (exact)
constexpr int PW_B  = (5 * D * D / 8 + 255) / 256;  // 40

typedef __bf16 bf16x8 __attribute__((ext_vector_type(8)));
typedef float  f32x4  __attribute__((ext_vector_type(4)));

__global__ void k_zero(int* __restrict__ p, int n) {
  int i = blockIdx.x * 256 + threadIdx.x;
  if (i < n) p[i] = 0;
}

// Fused: edge count (+rank) | x fp32->bf16 | W^T pack to bf16.
template <bool XB>
__global__ void k_prep(const int* __restrict__ dst, int* __restrict__ cnt,
                       int* __restrict__ rank, const float* __restrict__ x,
                       __bf16* __restrict__ xb, const float* __restrict__ W,
                       const float* __restrict__ Wself, __bf16* __restrict__ wt) {
  const int bid = blockIdx.x;
  const int tid = threadIdx.x;
  if (bid < CNT_B) {
    int i = bid * 256 + tid;
    if (i < T * E) {
      int t = i / E;
      rank[i] = atomicAdd(&cnt[t * N + dst[i]], 1);
    }
  } else if (XB && bid < CNT_B + PX_B) {
    int i = (bid - CNT_B) * 256 + tid;  // one per 8 floats
    if (i < N * D / 8) {
      const float4* xs = (const float4*)(x + i * 8);
      float4 a = xs[0], c = xs[1];
      bf16x8 v;
      v[0] = (__bf16)a.x; v[1] = (__bf16)a.y; v[2] = (__bf16)a.z; v[3] = (__bf16)a.w;
      v[4] = (__bf16)c.x; v[5] = (__bf16)c.y; v[6] = (__bf16)c.z; v[7] = (__bf16)c.w;
      *(bf16x8*)(xb + i * 8) = v;
    }
  } else {
    int i = (bid - CNT_B - (XB ? PX_B : 0)) * 256 + tid;  // one per 8 wt elems
    if (i < 5 * D * D / 8) {
      int base = i * 8;
      int p = base >> 14, rem = base & 16383;
      int n = rem >> 7, k0 = rem & 127;
      const float* Wsrc = (p < 4) ? (W + (size_t)p * D * D) : Wself;  // [k][n]
      bf16x8 v;
#pragma unroll
      for (int j = 0; j < 8; ++j) v[j] = (__bf16)Wsrc[(k0 + j) * D + n];
      *(bf16x8*)(wt + base) = v;
    }
  }
}

// Exclusive offsets via block scan + one global-cursor atomic per block.
__global__ void k_offsets(const int* __restrict__ cnt, int* __restrict__ offs,
                          int* __restrict__ cursor) {
  __shared__ int s[256];
  __shared__ int base;
  int tid = threadIdx.x;
  int i = blockIdx.x * 256 + tid;
  int c = (i < T * N) ? cnt[i] : 0;
  s[tid] = c;
  __syncthreads();
  for (int d = 1; d < 256; d <<= 1) {
    int v = (tid >= d) ? s[tid - d] : 0;
    __syncthreads();
    s[tid] += v;
    __syncthreads();
  }
  if (tid == 255) base = atomicAdd(cursor, s[255]);
  __syncthreads();
  if (i < T * N) offs[i] = base + s[tid] - c;  // exclusive
}

// No atomics: pos = offs[bucket] + rank (rank recorded during count).
__global__ void k_scatter(const int* __restrict__ src, const int* __restrict__ dst,
                          const int* __restrict__ offs, const int* __restrict__ rank,
                          int* __restrict__ eid) {
  int i = blockIdx.x * 256 + threadIdx.x;
  if (i >= T * E) return;
  int t = i / E;
  int pos = offs[t * N + dst[i]] + rank[i];
  eid[pos] = src[i];
}

// Fused aggregate + bf16 MFMA GEMM. 256 threads (4 waves), 64-node tile.
// LDS: a_s only, 17408 B -> 6 blocks/CU (VGPR-bound at 24 waves/CU).
template <bool XB>
__global__ __launch_bounds__(256, 6) void k_fused(
    const float* __restrict__ x, const __bf16* __restrict__ xb,
    const __bf16* __restrict__ wt, const float* __restrict__ b,
    const float* __restrict__ bself, const int* __restrict__ cnt,
    const int* __restrict__ offs, const int* __restrict__ eid,
    float* __restrict__ out) {
  __shared__ __align__(16) __bf16 a_s[NT * AS];  // 17408 B

  const int tid  = threadIdx.x;
  const int nb   = blockIdx.x * NT;
  const int wv   = tid >> 6;
  const int lane = tid & 63;
  const int quad = lane >> 4;
  const int l16  = lane & 15;
  const int ln   = tid >> 2;   // staging node 0..63
  const int q    = tid & 3;    // staging k-quarter: k = q*32 .. q*32+31

  f32x4 acc[8];
#pragma unroll
  for (int ct = 0; ct < 8; ++ct) acc[ct] = (f32x4){0.f, 0.f, 0.f, 0.f};

  for (int pass = 0; pass < 5; ++pass) {
    const bool self = (pass == 4);

    // ---- stage a_s: mean-aggregated features (skipped for self-pass when XB)
    if (!(XB && self)) {
      float r[32];
#pragma unroll
      for (int i = 0; i < 32; ++i) r[i] = 0.f;
      const int node = nb + ln;
      if (self) {  // only reached when !XB
        const float4* xr = (const float4*)(x + (size_t)node * D + q * 32);
#pragma unroll
        for (int i = 0; i < 8; ++i) {
          float4 v = xr[i];
          r[4 * i] = v.x; r[4 * i + 1] = v.y; r[4 * i + 2] = v.z; r[4 * i + 3] = v.w;
        }
      } else {
        const int base = offs[pass * N + node];
        const int deg  = cnt[pass * N + node];
        int nxt = (deg > 0) ? eid[base] : 0;
        for (int e = 0; e < deg; ++e) {
          const int sidx = nxt;
          nxt = eid[base + e + 1];  // prefetch; reads slack/next bucket on last iter (harmless)
          if (XB) {
            const bf16x8* xr = (const bf16x8*)(xb + (size_t)sidx * D + q * 32);
            bf16x8 v0 = xr[0], v1 = xr[1], v2 = xr[2], v3 = xr[3];
#pragma unroll
            for (int j = 0; j < 8; ++j) {
              r[j]      += (float)v0[j];
              r[8 + j]  += (float)v1[j];
              r[16 + j] += (float)v2[j];
              r[24 + j] += (float)v3[j];
            }
          } else {
            const float4* xr = (const float4*)(x + (size_t)sidx * D + q * 32);
#pragma unroll
            for (int i = 0; i < 8; ++i) {
              float4 v = xr[i];
              r[4 * i] += v.x; r[4 * i + 1] += v.y;
              r[4 * i + 2] += v.z; r[4 * i + 3] += v.w;
            }
          }
        }
        const float inv = (deg > 0) ? (1.0f / (float)deg) : 0.0f;
#pragma unroll
        for (int i = 0; i < 32; ++i) r[i] *= inv;
      }
      __bf16* arow = a_s + ln * AS + q * 32;
#pragma unroll
      for (int g = 0; g < 4; ++g) {
        bf16x8 v;
#pragma unroll
        for (int j = 0; j < 8; ++j) v[j] = (__bf16)r[8 * g + j];
        *(bf16x8*)(arow + g * 8) = v;
      }
    }
    __syncthreads();

    // ---- MFMA: A-frags from a_s (or xb for self-pass), B-frags from global wt.
    // A-frag: A[m=l16][k=quad*8+j]; B-frag: B[k=quad*8+j][n=l16] from wt[n][k].
#pragma unroll
    for (int ks = 0; ks < 4; ++ks) {
      bf16x8 af;
      if (XB && self) {
        af = *(const bf16x8*)(xb + (size_t)(nb + 16 * wv + l16) * D + ks * 32 +
                              quad * 8);
      } else {
        af = *(const bf16x8*)(a_s + (16 * wv + l16) * AS + ks * 32 + quad * 8);
      }
      const __bf16* wp = wt + pass * D * D + ks * 32 + quad * 8;
#pragma unroll
      for (int ct = 0; ct < 8; ++ct) {
        bf16x8 bfr = *(const bf16x8*)(wp + (16 * ct + l16) * D);
        acc[ct] = __builtin_amdgcn_mfma_f32_16x16x32_bf16(af, bfr, acc[ct], 0, 0, 0);
      }
    }

    // ---- bias: b[t] gated on deg>0 per output row; b_self unconditional.
    // C/D layout: col = 16*ct + l16, row = 16*wv + quad*4 + reg.
    {
      const float* bt = self ? bself : (b + pass * D);
      bool rowon[4];
#pragma unroll
      for (int r = 0; r < 4; ++r) {
        rowon[r] = self ? true : (cnt[pass * N + nb + 16 * wv + quad * 4 + r] > 0);
      }
#pragma unroll
      for (int ct = 0; ct < 8; ++ct) {
        const float bv = bt[16 * ct + l16];
#pragma unroll
        for (int r = 0; r < 4; ++r)
          if (rowon[r]) acc[ct][r] += bv;
      }
    }
    if (pass < 4) __syncthreads();  // guard a_s overwrite by next pass
  }

  // ---- epilogue: each store instr covers 4 full 64B lines (4 rows x 16 lanes)
#pragma unroll
  for (int ct = 0; ct < 8; ++ct) {
#pragma unroll
    for (int r = 0; r < 4; ++r) {
      out[(size_t)(nb + 16 * wv + quad * 4 + r) * D + 16 * ct + l16] = acc[ct][r];
    }
  }
}

}  // namespace

extern "C" void kernel_launch(void* const* d_in, const int* in_sizes, int n_in,
                              void* d_out, int out_size, void* d_ws, size_t ws_size,
                              hipStream_t stream) {
  const float* x     = (const float*)d_in[0];
  const float* W     = (const float*)d_in[1];
  const float* b     = (const float*)d_in[2];
  const float* Wself = (const float*)d_in[3];
  const float* bself = (const float*)d_in[4];
  const int*   src   = (const int*)d_in[5];
  const int*   dst   = (const int*)d_in[6];
  float* out = (float*)d_out;

  // ws (ints): cnt[T*N] | cursor(+pad)[4] | offs[T*N] | eid[T*E] | rank[T*E]
  //            then bf16: wt[5*D*D] | xb[N*D]
  int* cnt    = (int*)d_ws;
  int* cursor = cnt + T * N;
  int* offs   = cursor + 4;
  int* eid    = offs + T * N;
  int* rank   = eid + T * E;   // rank doubles as slack for eid's +1 prefetch
  __bf16* wt  = (__bf16*)(rank + T * E);
  __bf16* xb  = wt + 5 * D * D;

  const size_t need_xb =
      (size_t)(T * N + 4 + T * N + T * E + T * E) * 4 + (size_t)5 * D * D * 2 +
      (size_t)N * D * 2;
  const bool use_xb = ws_size >= need_xb;

  k_zero<<<(T * N + 4 + 255) / 256, 256, 0, stream>>>(cnt, T * N + 4);
  if (use_xb) {
    k_prep<true><<<CNT_B + PX_B + PW_B, 256, 0, stream>>>(dst, cnt, rank, x, xb,
                                                          W, Wself, wt);
  } else {
    k_prep<false><<<CNT_B + PW_B, 256, 0, stream>>>(dst, cnt, rank, x, xb, W,
                                                    Wself, wt);
  }
  k_offsets<<<(T * N + 255) / 256, 256, 0, stream>>>(cnt, offs, cursor);
  k_scatter<<<(T * E + 255) / 256, 256, 0, stream>>>(src, dst, offs, rank, eid);
  if (use_xb) {
    k_fused<true><<<N / NT, 256, 0, stream>>>(x, xb, wt, b, bself, cnt, offs,
                                              eid, out);
  } else {
    k_fused<false><<<N / NT, 256, 0, stream>>>(x, xb, wt, b, bself, cnt, offs,
                                               eid, out);
  }
}

// Round 6
// 723.687 us; speedup vs baseline: 2.4741x; 1.0832x over previous
//
#include <hip/hip_runtime.h>
#include <hip/hip_bf16.h>

// RGCN layer: out = x@W_self + b_self + sum_t [ mean_t(x[src]) @ W[t] + (deg_t>0)*b[t] ]
// v6: v5 with launch_bounds 6 -> 4. v5's (256,6) forced VGPR to 40 and SPILLED the
//     r[32] gather accumulator to scratch (WRITE_SIZE 100->589MB, VALUBusy 11%,
//     k_fused 460us). (256,4) keeps the VGPR cap at 128 (kernel needs ~76-84, no
//     spill) while still lifting occupancy to 4 blocks/CU (16 waves) vs v3's 3
//     blocks (LDS-bound at 52KB). Keeps v5's wins: w_s dropped from LDS (B-frags
//     from global wt, L1-resident 32KB/pass slab; bank conflicts 10.4M -> 2.4M),
//     LDS 17.4KB (a_s only).

namespace {

constexpr int N  = 200000;  // nodes
constexpr int T  = 4;       // etypes
constexpr int E  = 500000;  // edges per etype
constexpr int D  = 128;     // d_in == d_out
constexpr int NT = 64;      // nodes per block tile
constexpr int AS = 136;     // padded LDS row stride (bf16): 2-way bank alias only (free)

constexpr int CNT_B = (T * E + 255) / 256;      // 7813
constexpr int PX_B  = (N * D / 8) / 256;        // 12500 (exact)
constexpr int PW_B  = (5 * D * D / 8 + 255) / 256;  // 40

typedef __bf16 bf16x8 __attribute__((ext_vector_type(8)));
typedef float  f32x4  __attribute__((ext_vector_type(4)));

__global__ void k_zero(int* __restrict__ p, int n) {
  int i = blockIdx.x * 256 + threadIdx.x;
  if (i < n) p[i] = 0;
}

// Fused: edge count (+rank) | x fp32->bf16 | W^T pack to bf16.
template <bool XB>
__global__ void k_prep(const int* __restrict__ dst, int* __restrict__ cnt,
                       int* __restrict__ rank, const float* __restrict__ x,
                       __bf16* __restrict__ xb, const float* __restrict__ W,
                       const float* __restrict__ Wself, __bf16* __restrict__ wt) {
  const int bid = blockIdx.x;
  const int tid = threadIdx.x;
  if (bid < CNT_B) {
    int i = bid * 256 + tid;
    if (i < T * E) {
      int t = i / E;
      rank[i] = atomicAdd(&cnt[t * N + dst[i]], 1);
    }
  } else if (XB && bid < CNT_B + PX_B) {
    int i = (bid - CNT_B) * 256 + tid;  // one per 8 floats
    if (i < N * D / 8) {
      const float4* xs = (const float4*)(x + i * 8);
      float4 a = xs[0], c = xs[1];
      bf16x8 v;
      v[0] = (__bf16)a.x; v[1] = (__bf16)a.y; v[2] = (__bf16)a.z; v[3] = (__bf16)a.w;
      v[4] = (__bf16)c.x; v[5] = (__bf16)c.y; v[6] = (__bf16)c.z; v[7] = (__bf16)c.w;
      *(bf16x8*)(xb + i * 8) = v;
    }
  } else {
    int i = (bid - CNT_B - (XB ? PX_B : 0)) * 256 + tid;  // one per 8 wt elems
    if (i < 5 * D * D / 8) {
      int base = i * 8;
      int p = base >> 14, rem = base & 16383;
      int n = rem >> 7, k0 = rem & 127;
      const float* Wsrc = (p < 4) ? (W + (size_t)p * D * D) : Wself;  // [k][n]
      bf16x8 v;
#pragma unroll
      for (int j = 0; j < 8; ++j) v[j] = (__bf16)Wsrc[(k0 + j) * D + n];
      *(bf16x8*)(wt + base) = v;
    }
  }
}

// Exclusive offsets via block scan + one global-cursor atomic per block.
__global__ void k_offsets(const int* __restrict__ cnt, int* __restrict__ offs,
                          int* __restrict__ cursor) {
  __shared__ int s[256];
  __shared__ int base;
  int tid = threadIdx.x;
  int i = blockIdx.x * 256 + tid;
  int c = (i < T * N) ? cnt[i] : 0;
  s[tid] = c;
  __syncthreads();
  for (int d = 1; d < 256; d <<= 1) {
    int v = (tid >= d) ? s[tid - d] : 0;
    __syncthreads();
    s[tid] += v;
    __syncthreads();
  }
  if (tid == 255) base = atomicAdd(cursor, s[255]);
  __syncthreads();
  if (i < T * N) offs[i] = base + s[tid] - c;  // exclusive
}

// No atomics: pos = offs[bucket] + rank (rank recorded during count).
__global__ void k_scatter(const int* __restrict__ src, const int* __restrict__ dst,
                          const int* __restrict__ offs, const int* __restrict__ rank,
                          int* __restrict__ eid) {
  int i = blockIdx.x * 256 + threadIdx.x;
  if (i >= T * E) return;
  int t = i / E;
  int pos = offs[t * N + dst[i]] + rank[i];
  eid[pos] = src[i];
}

// Fused aggregate + bf16 MFMA GEMM. 256 threads (4 waves), 64-node tile.
// LDS: a_s only, 17408 B. launch_bounds(256,4): VGPR cap 128 (kernel ~80, no
// spill) -> 4 blocks/CU (16 waves/CU).
template <bool XB>
__global__ __launch_bounds__(256, 4) void k_fused(
    const float* __restrict__ x, const __bf16* __restrict__ xb,
    const __bf16* __restrict__ wt, const float* __restrict__ b,
    const float* __restrict__ bself, const int* __restrict__ cnt,
    const int* __restrict__ offs, const int* __restrict__ eid,
    float* __restrict__ out) {
  __shared__ __align__(16) __bf16 a_s[NT * AS];  // 17408 B

  const int tid  = threadIdx.x;
  const int nb   = blockIdx.x * NT;
  const int wv   = tid >> 6;
  const int lane = tid & 63;
  const int quad = lane >> 4;
  const int l16  = lane & 15;
  const int ln   = tid >> 2;   // staging node 0..63
  const int q    = tid & 3;    // staging k-quarter: k = q*32 .. q*32+31

  f32x4 acc[8];
#pragma unroll
  for (int ct = 0; ct < 8; ++ct) acc[ct] = (f32x4){0.f, 0.f, 0.f, 0.f};

  for (int pass = 0; pass < 5; ++pass) {
    const bool self = (pass == 4);

    // ---- stage a_s: mean-aggregated features (skipped for self-pass when XB)
    if (!(XB && self)) {
      float r[32];
#pragma unroll
      for (int i = 0; i < 32; ++i) r[i] = 0.f;
      const int node = nb + ln;
      if (self) {  // only reached when !XB
        const float4* xr = (const float4*)(x + (size_t)node * D + q * 32);
#pragma unroll
        for (int i = 0; i < 8; ++i) {
          float4 v = xr[i];
          r[4 * i] = v.x; r[4 * i + 1] = v.y; r[4 * i + 2] = v.z; r[4 * i + 3] = v.w;
        }
      } else {
        const int base = offs[pass * N + node];
        const int deg  = cnt[pass * N + node];
        int nxt = (deg > 0) ? eid[base] : 0;
        for (int e = 0; e < deg; ++e) {
          const int sidx = nxt;
          nxt = eid[base + e + 1];  // prefetch; reads slack/next bucket on last iter (harmless)
          if (XB) {
            const bf16x8* xr = (const bf16x8*)(xb + (size_t)sidx * D + q * 32);
            bf16x8 v0 = xr[0], v1 = xr[1], v2 = xr[2], v3 = xr[3];
#pragma unroll
            for (int j = 0; j < 8; ++j) {
              r[j]      += (float)v0[j];
              r[8 + j]  += (float)v1[j];
              r[16 + j] += (float)v2[j];
              r[24 + j] += (float)v3[j];
            }
          } else {
            const float4* xr = (const float4*)(x + (size_t)sidx * D + q * 32);
#pragma unroll
            for (int i = 0; i < 8; ++i) {
              float4 v = xr[i];
              r[4 * i] += v.x; r[4 * i + 1] += v.y;
              r[4 * i + 2] += v.z; r[4 * i + 3] += v.w;
            }
          }
        }
        const float inv = (deg > 0) ? (1.0f / (float)deg) : 0.0f;
#pragma unroll
        for (int i = 0; i < 32; ++i) r[i] *= inv;
      }
      __bf16* arow = a_s + ln * AS + q * 32;
#pragma unroll
      for (int g = 0; g < 4; ++g) {
        bf16x8 v;
#pragma unroll
        for (int j = 0; j < 8; ++j) v[j] = (__bf16)r[8 * g + j];
        *(bf16x8*)(arow + g * 8) = v;
      }
    }
    __syncthreads();

    // ---- MFMA: A-frags from a_s (or xb for self-pass), B-frags from global wt.
    // A-frag: A[m=l16][k=quad*8+j]; B-frag: B[k=quad*8+j][n=l16] from wt[n][k].
#pragma unroll
    for (int ks = 0; ks < 4; ++ks) {
      bf16x8 af;
      if (XB && self) {
        af = *(const bf16x8*)(xb + (size_t)(nb + 16 * wv + l16) * D + ks * 32 +
                              quad * 8);
      } else {
        af = *(const bf16x8*)(a_s + (16 * wv + l16) * AS + ks * 32 + quad * 8);
      }
      const __bf16* wp = wt + pass * D * D + ks * 32 + quad * 8;
#pragma unroll
      for (int ct = 0; ct < 8; ++ct) {
        bf16x8 bfr = *(const bf16x8*)(wp + (16 * ct + l16) * D);
        acc[ct] = __builtin_amdgcn_mfma_f32_16x16x32_bf16(af, bfr, acc[ct], 0, 0, 0);
      }
    }

    // ---- bias: b[t] gated on deg>0 per output row; b_self unconditional.
    // C/D layout: col = 16*ct + l16, row = 16*wv + quad*4 + reg.
    {
      const float* bt = self ? bself : (b + pass * D);
      bool rowon[4];
#pragma unroll
      for (int r = 0; r < 4; ++r) {
        rowon[r] = self ? true : (cnt[pass * N + nb + 16 * wv + quad * 4 + r] > 0);
      }
#pragma unroll
      for (int ct = 0; ct < 8; ++ct) {
        const float bv = bt[16 * ct + l16];
#pragma unroll
        for (int r = 0; r < 4; ++r)
          if (rowon[r]) acc[ct][r] += bv;
      }
    }
    if (pass < 4) __syncthreads();  // guard a_s overwrite by next pass
  }

  // ---- epilogue: each store instr covers 4 full 64B lines (4 rows x 16 lanes)
#pragma unroll
  for (int ct = 0; ct < 8; ++ct) {
#pragma unroll
    for (int r = 0; r < 4; ++r) {
      out[(size_t)(nb + 16 * wv + quad * 4 + r) * D + 16 * ct + l16] = acc[ct][r];
    }
  }
}

}  // namespace

extern "C" void kernel_launch(void* const* d_in, const int* in_sizes, int n_in,
                              void* d_out, int out_size, void* d_ws, size_t ws_size,
                              hipStream_t stream) {
  const float* x     = (const float*)d_in[0];
  const float* W     = (const float*)d_in[1];
  const float* b     = (const float*)d_in[2];
  const float* Wself = (const float*)d_in[3];
  const float* bself = (const float*)d_in[4];
  const int*   src   = (const int*)d_in[5];
  const int*   dst   = (const int*)d_in[6];
  float* out = (float*)d_out;

  // ws (ints): cnt[T*N] | cursor(+pad)[4] | offs[T*N] | eid[T*E] | rank[T*E]
  //            then bf16: wt[5*D*D] | xb[N*D]
  int* cnt    = (int*)d_ws;
  int* cursor = cnt + T * N;
  int* offs   = cursor + 4;
  int* eid    = offs + T * N;
  int* rank   = eid + T * E;   // rank doubles as slack for eid's +1 prefetch
  __bf16* wt  = (__bf16*)(rank + T * E);
  __bf16* xb  = wt + 5 * D * D;

  const size_t need_xb =
      (size_t)(T * N + 4 + T * N + T * E + T * E) * 4 + (size_t)5 * D * D * 2 +
      (size_t)N * D * 2;
  const bool use_xb = ws_size >= need_xb;

  k_zero<<<(T * N + 4 + 255) / 256, 256, 0, stream>>>(cnt, T * N + 4);
  if (use_xb) {
    k_prep<true><<<CNT_B + PX_B + PW_B, 256, 0, stream>>>(dst, cnt, rank, x, xb,
                                                          W, Wself, wt);
  } else {
    k_prep<false><<<CNT_B + PW_B, 256, 0, stream>>>(dst, cnt, rank, x, xb, W,
                                                    Wself, wt);
  }
  k_offsets<<<(T * N + 255) / 256, 256, 0, stream>>>(cnt, offs, cursor);
  k_scatter<<<(T * E + 255) / 256, 256, 0, stream>>>(src, dst, offs, rank, eid);
  if (use_xb) {
    k_fused<true><<<N / NT, 256, 0, stream>>>(x, xb, wt, b, bself, cnt, offs,
                                              eid, out);
  } else {
    k_fused<false><<<N / NT, 256, 0, stream>>>(x, xb, wt, b, bself, cnt, offs,
                                               eid, out);
  }
}

// Round 8
// 716.131 us; speedup vs baseline: 2.5002x; 1.0106x over previous
//
#include <hip/hip_runtime.h>
#include <hip/hip_bf16.h>

// RGCN layer: out = x@W_self + b_self + sum_t [ mean_t(x[src]) @ W[t] + (deg_t>0)*b[t] ]
// v7 (resubmit; prior round hit GPUAcquisitionTimeout, never measured):
//     v6 with launch_bounds (256,4) -> (256,3). Evidence trail:
//     - v5 (256,6): allocator hit the 64-VGPR HW step -> VGPR 40, massive spill.
//     - v6 (256,4): allocator STILL rounded to the 64-VGPR step -> spill remains
//       (WRITE 137MB vs 102MB output, VALUBusy 14%).
//     - v3 (256,3): same code shape allocated 76 VGPR, zero spill (WRITE=100MB).
//     At VGPR 76 the HW grants 4 waves/SIMD anyway (step at 128); occupancy is now
//     LDS/VGPR-step-bound at 4 blocks/CU (16 waves) since LDS is only 17.4KB
//     (w_s dropped; B-frags from global wt, L1/L2-resident 32KB/pass slab).
//     So (256,3) here = no-spill 76-VGPR alloc + 16 waves/CU (v3 had 12, LDS-bound).

namespace {

constexpr int N  = 200000;  // nodes
constexpr int T  = 4;       // etypes
constexpr int E  = 500000;  // edges per etype
constexpr int D  = 128;     // d_in == d_out
constexpr int NT = 64;      // nodes per block tile
constexpr int AS = 136;     // padded LDS row stride (bf16): 2-way bank alias only (free)

constexpr int CNT_B = (T * E + 255) / 256;      // 7813
constexpr int PX_B  = (N * D / 8) / 256;        // 12500 (exact)
constexpr int PW_B  = (5 * D * D / 8 + 255) / 256;  // 40

typedef __bf16 bf16x8 __attribute__((ext_vector_type(8)));
typedef float  f32x4  __attribute__((ext_vector_type(4)));

__global__ void k_zero(int* __restrict__ p, int n) {
  int i = blockIdx.x * 256 + threadIdx.x;
  if (i < n) p[i] = 0;
}

// Fused: edge count (+rank) | x fp32->bf16 | W^T pack to bf16.
template <bool XB>
__global__ void k_prep(const int* __restrict__ dst, int* __restrict__ cnt,
                       int* __restrict__ rank, const float* __restrict__ x,
                       __bf16* __restrict__ xb, const float* __restrict__ W,
                       const float* __restrict__ Wself, __bf16* __restrict__ wt) {
  const int bid = blockIdx.x;
  const int tid = threadIdx.x;
  if (bid < CNT_B) {
    int i = bid * 256 + tid;
    if (i < T * E) {
      int t = i / E;
      rank[i] = atomicAdd(&cnt[t * N + dst[i]], 1);
    }
  } else if (XB && bid < CNT_B + PX_B) {
    int i = (bid - CNT_B) * 256 + tid;  // one per 8 floats
    if (i < N * D / 8) {
      const float4* xs = (const float4*)(x + i * 8);
      float4 a = xs[0], c = xs[1];
      bf16x8 v;
      v[0] = (__bf16)a.x; v[1] = (__bf16)a.y; v[2] = (__bf16)a.z; v[3] = (__bf16)a.w;
      v[4] = (__bf16)c.x; v[5] = (__bf16)c.y; v[6] = (__bf16)c.z; v[7] = (__bf16)c.w;
      *(bf16x8*)(xb + i * 8) = v;
    }
  } else {
    int i = (bid - CNT_B - (XB ? PX_B : 0)) * 256 + tid;  // one per 8 wt elems
    if (i < 5 * D * D / 8) {
      int base = i * 8;
      int p = base >> 14, rem = base & 16383;
      int n = rem >> 7, k0 = rem & 127;
      const float* Wsrc = (p < 4) ? (W + (size_t)p * D * D) : Wself;  // [k][n]
      bf16x8 v;
#pragma unroll
      for (int j = 0; j < 8; ++j) v[j] = (__bf16)Wsrc[(k0 + j) * D + n];
      *(bf16x8*)(wt + base) = v;
    }
  }
}

// Exclusive offsets via block scan + one global-cursor atomic per block.
__global__ void k_offsets(const int* __restrict__ cnt, int* __restrict__ offs,
                          int* __restrict__ cursor) {
  __shared__ int s[256];
  __shared__ int base;
  int tid = threadIdx.x;
  int i = blockIdx.x * 256 + tid;
  int c = (i < T * N) ? cnt[i] : 0;
  s[tid] = c;
  __syncthreads();
  for (int d = 1; d < 256; d <<= 1) {
    int v = (tid >= d) ? s[tid - d] : 0;
    __syncthreads();
    s[tid] += v;
    __syncthreads();
  }
  if (tid == 255) base = atomicAdd(cursor, s[255]);
  __syncthreads();
  if (i < T * N) offs[i] = base + s[tid] - c;  // exclusive
}

// No atomics: pos = offs[bucket] + rank (rank recorded during count).
__global__ void k_scatter(const int* __restrict__ src, const int* __restrict__ dst,
                          const int* __restrict__ offs, const int* __restrict__ rank,
                          int* __restrict__ eid) {
  int i = blockIdx.x * 256 + threadIdx.x;
  if (i >= T * E) return;
  int t = i / E;
  int pos = offs[t * N + dst[i]] + rank[i];
  eid[pos] = src[i];
}

// Fused aggregate + bf16 MFMA GEMM. 256 threads (4 waves), 64-node tile.
// LDS: a_s only, 17408 B. launch_bounds(256,3): proven 76-VGPR no-spill alloc;
// HW then grants 4 waves/SIMD (VGPR<=128 step) -> 4 blocks/CU, 16 waves/CU.
template <bool XB>
__global__ __launch_bounds__(256, 3) void k_fused(
    const float* __restrict__ x, const __bf16* __restrict__ xb,
    const __bf16* __restrict__ wt, const float* __restrict__ b,
    const float* __restrict__ bself, const int* __restrict__ cnt,
    const int* __restrict__ offs, const int* __restrict__ eid,
    float* __restrict__ out) {
  __shared__ __align__(16) __bf16 a_s[NT * AS];  // 17408 B

  const int tid  = threadIdx.x;
  const int nb   = blockIdx.x * NT;
  const int wv   = tid >> 6;
  const int lane = tid & 63;
  const int quad = lane >> 4;
  const int l16  = lane & 15;
  const int ln   = tid >> 2;   // staging node 0..63
  const int q    = tid & 3;    // staging k-quarter: k = q*32 .. q*32+31

  f32x4 acc[8];
#pragma unroll
  for (int ct = 0; ct < 8; ++ct) acc[ct] = (f32x4){0.f, 0.f, 0.f, 0.f};

  for (int pass = 0; pass < 5; ++pass) {
    const bool self = (pass == 4);

    // ---- stage a_s: mean-aggregated features (skipped for self-pass when XB)
    if (!(XB && self)) {
      float r[32];
#pragma unroll
      for (int i = 0; i < 32; ++i) r[i] = 0.f;
      const int node = nb + ln;
      if (self) {  // only reached when !XB
        const float4* xr = (const float4*)(x + (size_t)node * D + q * 32);
#pragma unroll
        for (int i = 0; i < 8; ++i) {
          float4 v = xr[i];
          r[4 * i] = v.x; r[4 * i + 1] = v.y; r[4 * i + 2] = v.z; r[4 * i + 3] = v.w;
        }
      } else {
        const int base = offs[pass * N + node];
        const int deg  = cnt[pass * N + node];
        int nxt = (deg > 0) ? eid[base] : 0;
        for (int e = 0; e < deg; ++e) {
          const int sidx = nxt;
          nxt = eid[base + e + 1];  // prefetch; reads slack/next bucket on last iter (harmless)
          if (XB) {
            const bf16x8* xr = (const bf16x8*)(xb + (size_t)sidx * D + q * 32);
            bf16x8 v0 = xr[0], v1 = xr[1], v2 = xr[2], v3 = xr[3];
#pragma unroll
            for (int j = 0; j < 8; ++j) {
              r[j]      += (float)v0[j];
              r[8 + j]  += (float)v1[j];
              r[16 + j] += (float)v2[j];
              r[24 + j] += (float)v3[j];
            }
          } else {
            const float4* xr = (const float4*)(x + (size_t)sidx * D + q * 32);
#pragma unroll
            for (int i = 0; i < 8; ++i) {
              float4 v = xr[i];
              r[4 * i] += v.x; r[4 * i + 1] += v.y;
              r[4 * i + 2] += v.z; r[4 * i + 3] += v.w;
            }
          }
        }
        const float inv = (deg > 0) ? (1.0f / (float)deg) : 0.0f;
#pragma unroll
        for (int i = 0; i < 32; ++i) r[i] *= inv;
      }
      __bf16* arow = a_s + ln * AS + q * 32;
#pragma unroll
      for (int g = 0; g < 4; ++g) {
        bf16x8 v;
#pragma unroll
        for (int j = 0; j < 8; ++j) v[j] = (__bf16)r[8 * g + j];
        *(bf16x8*)(arow + g * 8) = v;
      }
    }
    __syncthreads();

    // ---- MFMA: A-frags from a_s (or xb for self-pass), B-frags from global wt.
    // A-frag: A[m=l16][k=quad*8+j]; B-frag: B[k=quad*8+j][n=l16] from wt[n][k].
#pragma unroll
    for (int ks = 0; ks < 4; ++ks) {
      bf16x8 af;
      if (XB && self) {
        af = *(const bf16x8*)(xb + (size_t)(nb + 16 * wv + l16) * D + ks * 32 +
                              quad * 8);
      } else {
        af = *(const bf16x8*)(a_s + (16 * wv + l16) * AS + ks * 32 + quad * 8);
      }
      const __bf16* wp = wt + pass * D * D + ks * 32 + quad * 8;
#pragma unroll
      for (int ct = 0; ct < 8; ++ct) {
        bf16x8 bfr = *(const bf16x8*)(wp + (16 * ct + l16) * D);
        acc[ct] = __builtin_amdgcn_mfma_f32_16x16x32_bf16(af, bfr, acc[ct], 0, 0, 0);
      }
    }

    // ---- bias: b[t] gated on deg>0 per output row; b_self unconditional.
    // C/D layout: col = 16*ct + l16, row = 16*wv + quad*4 + reg.
    {
      const float* bt = self ? bself : (b + pass * D);
      bool rowon[4];
#pragma unroll
      for (int r = 0; r < 4; ++r) {
        rowon[r] = self ? true : (cnt[pass * N + nb + 16 * wv + quad * 4 + r] > 0);
      }
#pragma unroll
      for (int ct = 0; ct < 8; ++ct) {
        const float bv = bt[16 * ct + l16];
#pragma unroll
        for (int r = 0; r < 4; ++r)
          if (rowon[r]) acc[ct][r] += bv;
      }
    }
    if (pass < 4) __syncthreads();  // guard a_s overwrite by next pass
  }

  // ---- epilogue: each store instr covers 4 full 64B lines (4 rows x 16 lanes)
#pragma unroll
  for (int ct = 0; ct < 8; ++ct) {
#pragma unroll
    for (int r = 0; r < 4; ++r) {
      out[(size_t)(nb + 16 * wv + quad * 4 + r) * D + 16 * ct + l16] = acc[ct][r];
    }
  }
}

}  // namespace

extern "C" void kernel_launch(void* const* d_in, const int* in_sizes, int n_in,
                              void* d_out, int out_size, void* d_ws, size_t ws_size,
                              hipStream_t stream) {
  const float* x     = (const float*)d_in[0];
  const float* W     = (const float*)d_in[1];
  const float* b     = (const float*)d_in[2];
  const float* Wself = (const float*)d_in[3];
  const float* bself = (const float*)d_in[4];
  const int*   src   = (const int*)d_in[5];
  const int*   dst   = (const int*)d_in[6];
  float* out = (float*)d_out;

  // ws (ints): cnt[T*N] | cursor(+pad)[4] | offs[T*N] | eid[T*E] | rank[T*E]
  //            then bf16: wt[5*D*D] | xb[N*D]
  int* cnt    = (int*)d_ws;
  int* cursor = cnt + T * N;
  int* offs   = cursor + 4;
  int* eid    = offs + T * N;
  int* rank   = eid + T * E;   // rank doubles as slack for eid's +1 prefetch
  __bf16* wt  = (__bf16*)(rank + T * E);
  __bf16* xb  = wt + 5 * D * D;

  const size_t need_xb =
      (size_t)(T * N + 4 + T * N + T * E + T * E) * 4 + (size_t)5 * D * D * 2 +
      (size_t)N * D * 2;
  const bool use_xb = ws_size >= need_xb;

  k_zero<<<(T * N + 4 + 255) / 256, 256, 0, stream>>>(cnt, T * N + 4);
  if (use_xb) {
    k_prep<true><<<CNT_B + PX_B + PW_B, 256, 0, stream>>>(dst, cnt, rank, x, xb,
                                                          W, Wself, wt);
  } else {
    k_prep<false><<<CNT_B + PW_B, 256, 0, stream>>>(dst, cnt, rank, x, xb, W,
                                                    Wself, wt);
  }
  k_offsets<<<(T * N + 255) / 256, 256, 0, stream>>>(cnt, offs, cursor);
  k_scatter<<<(T * E + 255) / 256, 256, 0, stream>>>(src, dst, offs, rank, eid);
  if (use_xb) {
    k_fused<true><<<N / NT, 256, 0, stream>>>(x, xb, wt, b, bself, cnt, offs,
                                              eid, out);
  } else {
    k_fused<false><<<N / NT, 256, 0, stream>>>(x, xb, wt, b, bself, cnt, offs,
                                               eid, out);
  }
}

// Round 11
// 611.295 us; speedup vs baseline: 2.9289x; 1.1715x over previous
//
#include <hip/hip_runtime.h>
#include <hip/hip_bf16.h>

// RGCN layer: out = x@W_self + b_self + sum_t [ mean_t(x[src]) @ W[t] + (deg_t>0)*b[t] ]
// v8 (3rd submit; rounds 9-10 hit GPUAcquisitionTimeout, never measured):
//     restore w_s LDS staging (v7 proved global B-frags add ~175us pure stall:
//     same FETCH/WRITE/occupancy as v3 but 382 vs 207us; VALU+MFMA absolute cycles
//     identical -> all added time was MFMA-loop stall on global wt loads).
//     Get occupancy a different way: 512-thread blocks, NT=128.
//     - LDS = a_s 34816 + w_s 34816 = 69632B -> 2 blocks/CU = 16 waves/CU
//       (v3: 52KB -> 3 blocks = 12 waves). gfx950 LDS is 160KB/CU, static >64KB ok.
//     - per-thread reg footprint unchanged (~72-76 VGPR, the proven no-spill shape);
//       launch_bounds(512,3): VGPR cap ~170, no allocator pressure (v5/v6's trap
//       was caps BELOW the ~76-reg live set).
//     - w_s staging amortized over 2x output rows (1563 blocks vs 3125).
//     - tail block (N%128=64): deg=0 for dead rows, clamped reads, guarded stores.

namespace {

constexpr int N  = 200000;  // nodes
constexpr int T  = 4;       // etypes
constexpr int E  = 500000;  // edges per etype
constexpr int D  = 128;     // d_in == d_out
constexpr int NT = 128;     // nodes per block tile (512 threads, 8 waves)
constexpr int AS = 136;     // padded LDS row stride (bf16): 2-way bank alias only (free)

constexpr int CNT_B = (T * E + 255) / 256;      // 7813
constexpr int PX_B  = (N * D / 8) / 256;        // 12500 (exact)
constexpr int PW_B  = (5 * D * D / 8 + 255) / 256;  // 40

typedef __bf16 bf16x8 __attribute__((ext_vector_type(8)));
typedef float  f32x4  __attribute__((ext_vector_type(4)));

__global__ void k_zero(int* __restrict__ p, int n) {
  int i = blockIdx.x * 256 + threadIdx.x;
  if (i < n) p[i] = 0;
}

// Fused: edge count (+rank) | x fp32->bf16 | W^T pack to bf16.
template <bool XB>
__global__ void k_prep(const int* __restrict__ dst, int* __restrict__ cnt,
                       int* __restrict__ rank, const float* __restrict__ x,
                       __bf16* __restrict__ xb, const float* __restrict__ W,
                       const float* __restrict__ Wself, __bf16* __restrict__ wt) {
  const int bid = blockIdx.x;
  const int tid = threadIdx.x;
  if (bid < CNT_B) {
    int i = bid * 256 + tid;
    if (i < T * E) {
      int t = i / E;
      rank[i] = atomicAdd(&cnt[t * N + dst[i]], 1);
    }
  } else if (XB && bid < CNT_B + PX_B) {
    int i = (bid - CNT_B) * 256 + tid;  // one per 8 floats
    if (i < N * D / 8) {
      const float4* xs = (const float4*)(x + i * 8);
      float4 a = xs[0], c = xs[1];
      bf16x8 v;
      v[0] = (__bf16)a.x; v[1] = (__bf16)a.y; v[2] = (__bf16)a.z; v[3] = (__bf16)a.w;
      v[4] = (__bf16)c.x; v[5] = (__bf16)c.y; v[6] = (__bf16)c.z; v[7] = (__bf16)c.w;
      *(bf16x8*)(xb + i * 8) = v;
    }
  } else {
    int i = (bid - CNT_B - (XB ? PX_B : 0)) * 256 + tid;  // one per 8 wt elems
    if (i < 5 * D * D / 8) {
      int base = i * 8;
      int p = base >> 14, rem = base & 16383;
      int n = rem >> 7, k0 = rem & 127;
      const float* Wsrc = (p < 4) ? (W + (size_t)p * D * D) : Wself;  // [k][n]
      bf16x8 v;
#pragma unroll
      for (int j = 0; j < 8; ++j) v[j] = (__bf16)Wsrc[(k0 + j) * D + n];
      *(bf16x8*)(wt + base) = v;
    }
  }
}

// Exclusive offsets via block scan + one global-cursor atomic per block.
__global__ void k_offsets(const int* __restrict__ cnt, int* __restrict__ offs,
                          int* __restrict__ cursor) {
  __shared__ int s[256];
  __shared__ int base;
  int tid = threadIdx.x;
  int i = blockIdx.x * 256 + tid;
  int c = (i < T * N) ? cnt[i] : 0;
  s[tid] = c;
  __syncthreads();
  for (int d = 1; d < 256; d <<= 1) {
    int v = (tid >= d) ? s[tid - d] : 0;
    __syncthreads();
    s[tid] += v;
    __syncthreads();
  }
  if (tid == 255) base = atomicAdd(cursor, s[255]);
  __syncthreads();
  if (i < T * N) offs[i] = base + s[tid] - c;  // exclusive
}

// No atomics: pos = offs[bucket] + rank (rank recorded during count).
__global__ void k_scatter(const int* __restrict__ src, const int* __restrict__ dst,
                          const int* __restrict__ offs, const int* __restrict__ rank,
                          int* __restrict__ eid) {
  int i = blockIdx.x * 256 + threadIdx.x;
  if (i >= T * E) return;
  int t = i / E;
  int pos = offs[t * N + dst[i]] + rank[i];
  eid[pos] = src[i];
}

// Fused aggregate + bf16 MFMA GEMM. 512 threads (8 waves), 128-node tile.
// LDS: a_s 34816 + w_s 34816 = 69632B -> 2 blocks/CU (16 waves/CU).
template <bool XB>
__global__ __launch_bounds__(512, 3) void k_fused(
    const float* __restrict__ x, const __bf16* __restrict__ xb,
    const __bf16* __restrict__ wt, const float* __restrict__ b,
    const float* __restrict__ bself, const int* __restrict__ cnt,
    const int* __restrict__ offs, const int* __restrict__ eid,
    float* __restrict__ out) {
  __shared__ __align__(16) __bf16 a_s[NT * AS];  // 34816 B
  __shared__ __align__(16) __bf16 w_s[D * AS];   // 34816 B

  const int tid  = threadIdx.x;
  const int nb   = blockIdx.x * NT;
  const int wv   = tid >> 6;   // wave 0..7 -> rows 16*wv..16*wv+15
  const int lane = tid & 63;
  const int quad = lane >> 4;
  const int l16  = lane & 15;
  const int ln   = tid >> 2;   // staging node 0..127
  const int q    = tid & 3;    // staging k-quarter: k = q*32 .. q*32+31

  f32x4 acc[8];
#pragma unroll
  for (int ct = 0; ct < 8; ++ct) acc[ct] = (f32x4){0.f, 0.f, 0.f, 0.f};

  for (int pass = 0; pass < 5; ++pass) {
    const bool self = (pass == 4);

    // ---- stage w_s first (issue before gather; overlaps gather latency)
    {
      const __bf16* wsrc = wt + pass * D * D;
#pragma unroll
      for (int c = 0; c < 4; ++c) {
        int idx  = c * 512 + tid;
        int row  = idx >> 4;
        int col8 = (idx & 15) * 8;
        *(bf16x8*)(w_s + row * AS + col8) = *(const bf16x8*)(wsrc + row * D + col8);
      }
    }

    // ---- stage a_s: mean-aggregated features (skipped for self-pass when XB)
    if (!(XB && self)) {
      float r[32];
#pragma unroll
      for (int i = 0; i < 32; ++i) r[i] = 0.f;
      const int node = nb + ln;  // may be >= N in tail block
      if (self) {  // only reached when !XB
        const int nc = (node < N) ? node : (N - 1);  // clamp: stay in-bounds
        const float4* xr = (const float4*)(x + (size_t)nc * D + q * 32);
#pragma unroll
        for (int i = 0; i < 8; ++i) {
          float4 v = xr[i];
          r[4 * i] = v.x; r[4 * i + 1] = v.y; r[4 * i + 2] = v.z; r[4 * i + 3] = v.w;
        }
      } else {
        const int deg  = (node < N) ? cnt[pass * N + node] : 0;
        const int base = (node < N) ? offs[pass * N + node] : 0;
        int nxt = (deg > 0) ? eid[base] : 0;
        for (int e = 0; e < deg; ++e) {
          const int sidx = nxt;
          nxt = eid[base + e + 1];  // prefetch; reads slack/next bucket on last iter (harmless)
          if (XB) {
            const bf16x8* xr = (const bf16x8*)(xb + (size_t)sidx * D + q * 32);
            bf16x8 v0 = xr[0], v1 = xr[1], v2 = xr[2], v3 = xr[3];
#pragma unroll
            for (int j = 0; j < 8; ++j) {
              r[j]      += (float)v0[j];
              r[8 + j]  += (float)v1[j];
              r[16 + j] += (float)v2[j];
              r[24 + j] += (float)v3[j];
            }
          } else {
            const float4* xr = (const float4*)(x + (size_t)sidx * D + q * 32);
#pragma unroll
            for (int i = 0; i < 8; ++i) {
              float4 v = xr[i];
              r[4 * i] += v.x; r[4 * i + 1] += v.y;
              r[4 * i + 2] += v.z; r[4 * i + 3] += v.w;
            }
          }
        }
        const float inv = (deg > 0) ? (1.0f / (float)deg) : 0.0f;
#pragma unroll
        for (int i = 0; i < 32; ++i) r[i] *= inv;
      }
      __bf16* arow = a_s + ln * AS + q * 32;
#pragma unroll
      for (int g = 0; g < 4; ++g) {
        bf16x8 v;
#pragma unroll
        for (int j = 0; j < 8; ++j) v[j] = (__bf16)r[8 * g + j];
        *(bf16x8*)(arow + g * 8) = v;
      }
    }
    __syncthreads();

    // ---- MFMA: A-frags from a_s (xb direct for self-pass), B-frags from w_s.
    // A-frag: A[m=l16][k=quad*8+j]; B-frag: B[k=quad*8+j][n=l16] from wt[n][k].
#pragma unroll
    for (int ks = 0; ks < 4; ++ks) {
      bf16x8 af;
      if (XB && self) {
        int row = nb + 16 * wv + l16;
        if (row >= N) row = N - 1;  // clamp: tail reads valid memory, store guarded
        af = *(const bf16x8*)(xb + (size_t)row * D + ks * 32 + quad * 8);
      } else {
        af = *(const bf16x8*)(a_s + (16 * wv + l16) * AS + ks * 32 + quad * 8);
      }
#pragma unroll
      for (int ct = 0; ct < 8; ++ct) {
        bf16x8 bfr = *(const bf16x8*)(w_s + (16 * ct + l16) * AS + ks * 32 + quad * 8);
        acc[ct] = __builtin_amdgcn_mfma_f32_16x16x32_bf16(af, bfr, acc[ct], 0, 0, 0);
      }
    }

    // ---- bias: b[t] gated on deg>0 per output row; b_self unconditional.
    // C/D layout: col = 16*ct + l16, row = 16*wv + quad*4 + reg.
    {
      const float* bt = self ? bself : (b + pass * D);
      bool rowon[4];
#pragma unroll
      for (int r = 0; r < 4; ++r) {
        // tail rows: cnt read overruns into cursor/offs region (in-bounds of ws,
        // garbage) but those rows are never stored.
        rowon[r] = self ? true : (cnt[pass * N + nb + 16 * wv + quad * 4 + r] > 0);
      }
#pragma unroll
      for (int ct = 0; ct < 8; ++ct) {
        const float bv = bt[16 * ct + l16];
#pragma unroll
        for (int r = 0; r < 4; ++r)
          if (rowon[r]) acc[ct][r] += bv;
      }
    }
    if (pass < 4) __syncthreads();  // guard LDS overwrite by next pass
  }

  // ---- epilogue: each store covers full 64B lines (16 lanes x 4B contiguous)
#pragma unroll
  for (int ct = 0; ct < 8; ++ct) {
#pragma unroll
    for (int r = 0; r < 4; ++r) {
      const int row = nb + 16 * wv + quad * 4 + r;
      if (row < N) out[(size_t)row * D + 16 * ct + l16] = acc[ct][r];
    }
  }
}

}  // namespace

extern "C" void kernel_launch(void* const* d_in, const int* in_sizes, int n_in,
                              void* d_out, int out_size, void* d_ws, size_t ws_size,
                              hipStream_t stream) {
  const float* x     = (const float*)d_in[0];
  const float* W     = (const float*)d_in[1];
  const float* b     = (const float*)d_in[2];
  const float* Wself = (const float*)d_in[3];
  const float* bself = (const float*)d_in[4];
  const int*   src   = (const int*)d_in[5];
  const int*   dst   = (const int*)d_in[6];
  float* out = (float*)d_out;

  // ws (ints): cnt[T*N] | cursor(+pad)[4] | offs[T*N] | eid[T*E] | rank[T*E]
  //            then bf16: wt[5*D*D] | xb[N*D]
  int* cnt    = (int*)d_ws;
  int* cursor = cnt + T * N;
  int* offs   = cursor + 4;
  int* eid    = offs + T * N;
  int* rank   = eid + T * E;   // rank doubles as slack for eid's +1 prefetch
  __bf16* wt  = (__bf16*)(rank + T * E);
  __bf16* xb  = wt + 5 * D * D;

  const size_t need_xb =
      (size_t)(T * N + 4 + T * N + T * E + T * E) * 4 + (size_t)5 * D * D * 2 +
      (size_t)N * D * 2;
  const bool use_xb = ws_size >= need_xb;

  const int grid = (N + NT - 1) / NT;  // 1563 (tail block guarded)

  k_zero<<<(T * N + 4 + 255) / 256, 256, 0, stream>>>(cnt, T * N + 4);
  if (use_xb) {
    k_prep<true><<<CNT_B + PX_B + PW_B, 256, 0, stream>>>(dst, cnt, rank, x, xb,
                                                          W, Wself, wt);
  } else {
    k_prep<false><<<CNT_B + PW_B, 256, 0, stream>>>(dst, cnt, rank, x, xb, W,
                                                    Wself, wt);
  }
  k_offsets<<<(T * N + 255) / 256, 256, 0, stream>>>(cnt, offs, cursor);
  k_scatter<<<(T * E + 255) / 256, 256, 0, stream>>>(src, dst, offs, rank, eid);
  if (use_xb) {
    k_fused<true><<<grid, 512, 0, stream>>>(x, xb, wt, b, bself, cnt, offs,
                                            eid, out);
  } else {
    k_fused<false><<<grid, 512, 0, stream>>>(x, xb, wt, b, bself, cnt, offs,
                                             eid, out);
  }
}

// Round 13
// 539.297 us; speedup vs baseline: 3.3200x; 1.1335x over previous
//
#include <hip/hip_runtime.h>
#include <hip/hip_bf16.h>

// RGCN layer: out = x@W_self + b_self + sum_t [ mean_t(x[src]) @ W[t] + (deg_t>0)*b[t] ]
// v9 (resubmit; prior round hit GPUAcquisitionTimeout, never measured):
//     k_fused restored byte-identical to v3 (proven 207us; v4-v8 perturbations all
//     regressed: LDS atomics 1490, no-w_s 382, 512-thr 279 -- every delta was pure
//     stall, VALU/MFMA absolute cycles constant). New target: the prep chain,
//     stable at ~330-338us (62% of total) across all rounds.
//     - k_prep count + k_scatter: 4 edges/thread via int4 (E%4==0 so a pack never
//       straddles an etype; rank written as one int4; bases 16B-aligned).
//     - k_zero: int4.
//     Atomic count unchanged; per-edge instruction + launch overhead ~4x lower.

namespace {

constexpr int N  = 200000;  // nodes
constexpr int T  = 4;       // etypes
constexpr int E  = 500000;  // edges per etype
constexpr int D  = 128;     // d_in == d_out
constexpr int NT = 64;      // nodes per block tile
constexpr int AS = 136;     // padded LDS row stride (bf16): 2-way bank alias only (free)

constexpr int CNT_B = (T * E / 4 + 255) / 256;  // 1954 (4 edges/thread)
constexpr int PX_B  = (N * D / 8) / 256;        // 12500 (exact)
constexpr int PW_B  = (5 * D * D / 8 + 255) / 256;  // 40
constexpr int SC_B  = (T * E / 4 + 255) / 256;  // 1954

typedef __bf16 bf16x8 __attribute__((ext_vector_type(8)));
typedef float  f32x4  __attribute__((ext_vector_type(4)));

__global__ void k_zero(int* __restrict__ p, int n) {
  int i = blockIdx.x * 256 + threadIdx.x;
  int4 z = {0, 0, 0, 0};
  if (i * 4 + 3 < n) {
    *(int4*)(p + i * 4) = z;
  } else {
    for (int j = i * 4; j < n; ++j) p[j] = 0;
  }
}

// Fused: edge count (+rank, 4 edges/thread) | x fp32->bf16 | W^T pack to bf16.
template <bool XB>
__global__ void k_prep(const int* __restrict__ dst, int* __restrict__ cnt,
                       int* __restrict__ rank, const float* __restrict__ x,
                       __bf16* __restrict__ xb, const float* __restrict__ W,
                       const float* __restrict__ Wself, __bf16* __restrict__ wt) {
  const int bid = blockIdx.x;
  const int tid = threadIdx.x;
  if (bid < CNT_B) {
    int i0 = (bid * 256 + tid) * 4;
    if (i0 < T * E) {
      int t = i0 / E;                  // pack never straddles etype (E%4==0)
      int4 d = *(const int4*)(dst + i0);
      int4 r;
      r.x = atomicAdd(&cnt[t * N + d.x], 1);
      r.y = atomicAdd(&cnt[t * N + d.y], 1);
      r.z = atomicAdd(&cnt[t * N + d.z], 1);
      r.w = atomicAdd(&cnt[t * N + d.w], 1);
      *(int4*)(rank + i0) = r;
    }
  } else if (XB && bid < CNT_B + PX_B) {
    int i = (bid - CNT_B) * 256 + tid;  // one per 8 floats
    if (i < N * D / 8) {
      const float4* xs = (const float4*)(x + i * 8);
      float4 a = xs[0], c = xs[1];
      bf16x8 v;
      v[0] = (__bf16)a.x; v[1] = (__bf16)a.y; v[2] = (__bf16)a.z; v[3] = (__bf16)a.w;
      v[4] = (__bf16)c.x; v[5] = (__bf16)c.y; v[6] = (__bf16)c.z; v[7] = (__bf16)c.w;
      *(bf16x8*)(xb + i * 8) = v;
    }
  } else {
    int i = (bid - CNT_B - (XB ? PX_B : 0)) * 256 + tid;  // one per 8 wt elems
    if (i < 5 * D * D / 8) {
      int base = i * 8;
      int p = base >> 14, rem = base & 16383;
      int n = rem >> 7, k0 = rem & 127;
      const float* Wsrc = (p < 4) ? (W + (size_t)p * D * D) : Wself;  // [k][n]
      bf16x8 v;
#pragma unroll
      for (int j = 0; j < 8; ++j) v[j] = (__bf16)Wsrc[(k0 + j) * D + n];
      *(bf16x8*)(wt + base) = v;
    }
  }
}

// Exclusive offsets via block scan + one global-cursor atomic per block.
__global__ void k_offsets(const int* __restrict__ cnt, int* __restrict__ offs,
                          int* __restrict__ cursor) {
  __shared__ int s[256];
  __shared__ int base;
  int tid = threadIdx.x;
  int i = blockIdx.x * 256 + tid;
  int c = (i < T * N) ? cnt[i] : 0;
  s[tid] = c;
  __syncthreads();
  for (int d = 1; d < 256; d <<= 1) {
    int v = (tid >= d) ? s[tid - d] : 0;
    __syncthreads();
    s[tid] += v;
    __syncthreads();
  }
  if (tid == 255) base = atomicAdd(cursor, s[255]);
  __syncthreads();
  if (i < T * N) offs[i] = base + s[tid] - c;  // exclusive
}

// No atomics: pos = offs[bucket] + rank (4 edges/thread, int4 reads).
__global__ void k_scatter(const int* __restrict__ src, const int* __restrict__ dst,
                          const int* __restrict__ offs, const int* __restrict__ rank,
                          int* __restrict__ eid) {
  int i0 = (blockIdx.x * 256 + threadIdx.x) * 4;
  if (i0 >= T * E) return;
  const int tb = (i0 / E) * N;  // pack never straddles etype
  int4 s = *(const int4*)(src + i0);
  int4 d = *(const int4*)(dst + i0);
  int4 r = *(const int4*)(rank + i0);
  eid[offs[tb + d.x] + r.x] = s.x;
  eid[offs[tb + d.y] + r.y] = s.y;
  eid[offs[tb + d.z] + r.z] = s.z;
  eid[offs[tb + d.w] + r.w] = s.w;
}

// Fused aggregate + bf16 MFMA GEMM. 256 threads (4 waves), 64-node tile.
// LDS: a_s 17408 B + w_s 34816 B = 52224 B -> 3 blocks/CU.  (v3, proven 207us)
template <bool XB>
__global__ __launch_bounds__(256, 3) void k_fused(
    const float* __restrict__ x, const __bf16* __restrict__ xb,
    const __bf16* __restrict__ wt, const float* __restrict__ b,
    const float* __restrict__ bself, const int* __restrict__ cnt,
    const int* __restrict__ offs, const int* __restrict__ eid,
    float* __restrict__ out) {
  __shared__ __align__(16) __bf16 a_s[NT * AS];
  __shared__ __align__(16) __bf16 w_s[D * AS];

  const int tid  = threadIdx.x;
  const int nb   = blockIdx.x * NT;
  const int wv   = tid >> 6;
  const int lane = tid & 63;
  const int quad = lane >> 4;
  const int l16  = lane & 15;
  const int ln   = tid >> 2;   // staging node 0..63
  const int q    = tid & 3;    // staging k-quarter: k = q*32 .. q*32+31

  f32x4 acc[8];
#pragma unroll
  for (int ct = 0; ct < 8; ++ct) acc[ct] = (f32x4){0.f, 0.f, 0.f, 0.f};

  for (int pass = 0; pass < 5; ++pass) {
    const bool self = (pass == 4);

    // ---- stage w_s (issue first; overlaps gather latency)
    {
      const __bf16* wsrc = wt + pass * D * D;
#pragma unroll
      for (int c = 0; c < 8; ++c) {
        int idx  = c * 256 + tid;
        int row  = idx >> 4;
        int col8 = (idx & 15) * 8;
        *(bf16x8*)(w_s + row * AS + col8) = *(const bf16x8*)(wsrc + row * D + col8);
      }
    }

    // ---- stage a_s: mean-aggregated features (skipped for self-pass when XB)
    if (!(XB && self)) {
      float r[32];
#pragma unroll
      for (int i = 0; i < 32; ++i) r[i] = 0.f;
      const int node = nb + ln;
      if (self) {  // only reached when !XB
        const float4* xr = (const float4*)(x + node * D + q * 32);
#pragma unroll
        for (int i = 0; i < 8; ++i) {
          float4 v = xr[i];
          r[4 * i] = v.x; r[4 * i + 1] = v.y; r[4 * i + 2] = v.z; r[4 * i + 3] = v.w;
        }
      } else {
        const int base = offs[pass * N + node];
        const int deg  = cnt[pass * N + node];
        int nxt = (deg > 0) ? eid[base] : 0;
        for (int e = 0; e < deg; ++e) {
          const int sidx = nxt;
          nxt = eid[base + e + 1];  // prefetch; reads slack/next bucket on last iter (harmless)
          if (XB) {
            const bf16x8* xr = (const bf16x8*)(xb + sidx * D + q * 32);
            bf16x8 v0 = xr[0], v1 = xr[1], v2 = xr[2], v3 = xr[3];
#pragma unroll
            for (int j = 0; j < 8; ++j) {
              r[j]      += (float)v0[j];
              r[8 + j]  += (float)v1[j];
              r[16 + j] += (float)v2[j];
              r[24 + j] += (float)v3[j];
            }
          } else {
            const float4* xr = (const float4*)(x + sidx * D + q * 32);
#pragma unroll
            for (int i = 0; i < 8; ++i) {
              float4 v = xr[i];
              r[4 * i] += v.x; r[4 * i + 1] += v.y;
              r[4 * i + 2] += v.z; r[4 * i + 3] += v.w;
            }
          }
        }
        const float inv = (deg > 0) ? (1.0f / (float)deg) : 0.0f;
#pragma unroll
        for (int i = 0; i < 32; ++i) r[i] *= inv;
      }
      __bf16* arow = a_s + ln * AS + q * 32;
#pragma unroll
      for (int g = 0; g < 4; ++g) {
        bf16x8 v;
#pragma unroll
        for (int j = 0; j < 8; ++j) v[j] = (__bf16)r[8 * g + j];
        *(bf16x8*)(arow + g * 8) = v;
      }
    }
    __syncthreads();

    // ---- MFMA: acc[16 x 128 per wave] += A @ W^T-layout
    // A-frag: A[m=l16][k=quad*8+j]; B-frag: B[k=quad*8+j][n=l16] from wt[n][k].
#pragma unroll
    for (int ks = 0; ks < 4; ++ks) {
      bf16x8 af;
      if (XB && self) {
        af = *(const bf16x8*)(xb + (nb + 16 * wv + l16) * D + ks * 32 + quad * 8);
      } else {
        af = *(const bf16x8*)(a_s + (16 * wv + l16) * AS + ks * 32 + quad * 8);
      }
#pragma unroll
      for (int ct = 0; ct < 8; ++ct) {
        bf16x8 bfr = *(const bf16x8*)(w_s + (16 * ct + l16) * AS + ks * 32 + quad * 8);
        acc[ct] = __builtin_amdgcn_mfma_f32_16x16x32_bf16(af, bfr, acc[ct], 0, 0, 0);
      }
    }

    // ---- bias: b[t] gated on deg>0 per output row; b_self unconditional.
    // C/D layout: col = 16*ct + l16, row = 16*wv + quad*4 + reg.
    {
      const float* bt = self ? bself : (b + pass * D);
      bool rowon[4];
#pragma unroll
      for (int r = 0; r < 4; ++r) {
        rowon[r] = self ? true : (cnt[pass * N + nb + 16 * wv + quad * 4 + r] > 0);
      }
#pragma unroll
      for (int ct = 0; ct < 8; ++ct) {
        float bv = bt[16 * ct + l16];
#pragma unroll
        for (int r = 0; r < 4; ++r)
          if (rowon[r]) acc[ct][r] += bv;
      }
    }
    if (pass < 4) __syncthreads();  // guard LDS overwrite by next pass
  }

  // ---- epilogue: each store instr covers 4 full 64B lines (4 rows x 16 lanes)
#pragma unroll
  for (int ct = 0; ct < 8; ++ct) {
#pragma unroll
    for (int r = 0; r < 4; ++r) {
      out[(nb + 16 * wv + quad * 4 + r) * D + 16 * ct + l16] = acc[ct][r];
    }
  }
}

}  // namespace

extern "C" void kernel_launch(void* const* d_in, const int* in_sizes, int n_in,
                              void* d_out, int out_size, void* d_ws, size_t ws_size,
                              hipStream_t stream) {
  const float* x     = (const float*)d_in[0];
  const float* W     = (const float*)d_in[1];
  const float* b     = (const float*)d_in[2];
  const float* Wself = (const float*)d_in[3];
  const float* bself = (const float*)d_in[4];
  const int*   src   = (const int*)d_in[5];
  const int*   dst   = (const int*)d_in[6];
  float* out = (float*)d_out;

  // ws (ints): cnt[T*N] | cursor(+pad)[4] | offs[T*N] | eid[T*E] | rank[T*E]
  //            then bf16: wt[5*D*D] | xb[N*D]
  int* cnt    = (int*)d_ws;
  int* cursor = cnt + T * N;
  int* offs   = cursor + 4;
  int* eid    = offs + T * N;
  int* rank   = eid + T * E;   // rank doubles as slack for eid's +1 prefetch
  __bf16* wt  = (__bf16*)(rank + T * E);
  __bf16* xb  = wt + 5 * D * D;

  const size_t need_xb =
      (size_t)(T * N + 4 + T * N + T * E + T * E) * 4 + (size_t)5 * D * D * 2 +
      (size_t)N * D * 2;
  const bool use_xb = ws_size >= need_xb;

  k_zero<<<(T * N + 4 + 1023) / 1024, 256, 0, stream>>>(cnt, T * N + 4);
  if (use_xb) {
    k_prep<true><<<CNT_B + PX_B + PW_B, 256, 0, stream>>>(dst, cnt, rank, x, xb,
                                                          W, Wself, wt);
  } else {
    k_prep<false><<<CNT_B + PW_B, 256, 0, stream>>>(dst, cnt, rank, x, xb, W,
                                                    Wself, wt);
  }
  k_offsets<<<(T * N + 255) / 256, 256, 0, stream>>>(cnt, offs, cursor);
  k_scatter<<<SC_B, 256, 0, stream>>>(src, dst, offs, rank, eid);
  if (use_xb) {
    k_fused<true><<<N / NT, 256, 0, stream>>>(x, xb, wt, b, bself, cnt, offs,
                                              eid, out);
  } else {
    k_fused<false><<<N / NT, 256, 0, stream>>>(x, xb, wt, b, bself, cnt, offs,
                                               eid, out);
  }
}